// Round 2
// baseline (886.873 us; speedup 1.0000x reference)
//
#include <hip/hip_runtime.h>
#include <hip/hip_bf16.h>

#define NNODES 50000
#define NEDGES 800000
#define DD 128

typedef unsigned int u32;
typedef unsigned short u16;

__device__ __forceinline__ u16 f2b(float f) {
    u32 u = __float_as_uint(f);
    u32 rounding = 0x7fffu + ((u >> 16) & 1u);
    return (u16)((u + rounding) >> 16);
}

// ---------------------------------------------------------------------------
// Phase 1: edge scatter into agg (= d_out, f32). One wave (64 lanes) per edge.
// Each lane handles 2 consecutive f32 features (float2 load -> 2 f32 atomics).
// ---------------------------------------------------------------------------
__global__ __launch_bounds__(256) void scatter_k(
    const float* __restrict__ x, const int* __restrict__ ei,
    float* __restrict__ agg, u32* __restrict__ deg) {
    u32 gid = blockIdx.x * 256u + threadIdx.x;
    u32 edge = gid >> 6;
    u32 lane = gid & 63u;
    if (edge >= NEDGES) return;
    int src = ei[edge];           // wave-uniform
    int dst = ei[NEDGES + edge];  // wave-uniform
    float2 v = ((const float2*)(x + (size_t)src * DD))[lane];  // coalesced row
    float* p = agg + (size_t)dst * DD + lane * 2u;
    unsafeAtomicAdd(p, v.x);
    unsafeAtomicAdd(p + 1, v.y);
    if (lane == 0) atomicAdd(deg + dst, 1u);
}

// ---------------------------------------------------------------------------
// Phase 2: tmp = (agg_sum * 1/max(deg,1)) @ W_l^T + b_l, IN PLACE over agg.
// W (f32 global) staged in LDS as bf16 pairs over out-dim o, row pitch 65
// dwords: staging writes hop banks by 1 (conflict-free), compute reads are
// 2-way (free per m136). Block = 256 = 4 nodes x 64 output-pairs.
// ---------------------------------------------------------------------------
__global__ __launch_bounds__(256) void lin_l_k(
    float* __restrict__ agg, const u32* __restrict__ deg,
    const float* __restrict__ Wl, const float* __restrict__ bl) {
    __shared__ u32 WT[DD * 65];
    __shared__ float rows[4 * DD];
    __shared__ float sbias[DD];
    const int tid = threadIdx.x;
    {
        u16* WTs = (u16*)WT;
        for (int i = tid; i < DD * DD; i += 256) {
            int o = i >> 7, k = i & 127;
            WTs[k * 130 + o] = f2b(Wl[i]);  // global read coalesced over k
        }
        if (tid < DD) sbias[tid] = bl[tid];
    }
    __syncthreads();
    const int h = tid & 63;
    const int nl = tid >> 6;
    const int n_stage = tid >> 6, c_stage = tid & 63;
    for (int base = blockIdx.x * 4; base < NNODES; base += gridDim.x * 4) {
        ((float2*)rows)[tid] =
            ((const float2*)(agg + (size_t)(base + n_stage) * DD))[c_stage];
        __syncthreads();
        float inv = 1.0f / fmaxf((float)deg[base + nl], 1.0f);
        float acc0 = 0.f, acc1 = 0.f;
#pragma unroll
        for (int k = 0; k < DD; ++k) {
            float a = rows[nl * DD + k];  // wave-uniform broadcast
            u32 w2 = WT[k * 65 + h];
            acc0 = fmaf(a, __uint_as_float(w2 << 16), acc0);
            acc1 = fmaf(a, __uint_as_float(w2 & 0xffff0000u), acc1);
        }
        acc0 = fmaf(acc0, inv, sbias[2 * h]);
        acc1 = fmaf(acc1, inv, sbias[2 * h + 1]);
        __syncthreads();  // all LDS row reads done before overwrite
        ((float2*)(agg + (size_t)(base + nl) * DD))[h] = make_float2(acc0, acc1);
    }
}

// ---------------------------------------------------------------------------
// Phase 3: out = relu(tmp + x @ W_r^T), IN PLACE over tmp (= d_out).
// Each thread reads exactly the float2 it overwrites -> no hazard.
// ---------------------------------------------------------------------------
__global__ __launch_bounds__(256) void lin_r_k(
    float* __restrict__ io, const float* __restrict__ x,
    const float* __restrict__ Wr) {
    __shared__ u32 WT[DD * 65];
    __shared__ float rows[4 * DD];
    const int tid = threadIdx.x;
    {
        u16* WTs = (u16*)WT;
        for (int i = tid; i < DD * DD; i += 256) {
            int o = i >> 7, k = i & 127;
            WTs[k * 130 + o] = f2b(Wr[i]);
        }
    }
    __syncthreads();
    const int h = tid & 63;
    const int nl = tid >> 6;
    const int n_stage = tid >> 6, c_stage = tid & 63;
    for (int base = blockIdx.x * 4; base < NNODES; base += gridDim.x * 4) {
        ((float2*)rows)[tid] =
            ((const float2*)(x + (size_t)(base + n_stage) * DD))[c_stage];
        __syncthreads();
        float2 t2 = ((const float2*)(io + (size_t)(base + nl) * DD))[h];
        float acc0 = t2.x, acc1 = t2.y;
#pragma unroll
        for (int k = 0; k < DD; ++k) {
            float a = rows[nl * DD + k];
            u32 w2 = WT[k * 65 + h];
            acc0 = fmaf(a, __uint_as_float(w2 << 16), acc0);
            acc1 = fmaf(a, __uint_as_float(w2 & 0xffff0000u), acc1);
        }
        acc0 = fmaxf(acc0, 0.f);
        acc1 = fmaxf(acc1, 0.f);
        __syncthreads();  // all LDS row reads done before next staging
        ((float2*)(io + (size_t)(base + nl) * DD))[h] = make_float2(acc0, acc1);
    }
}

extern "C" void kernel_launch(void* const* d_in, const int* in_sizes, int n_in,
                              void* d_out, int out_size, void* d_ws, size_t ws_size,
                              hipStream_t stream) {
    const float* x  = (const float*)d_in[0];
    const int*   ei = (const int*)d_in[1];
    const float* Wl = (const float*)d_in[2];
    const float* bl = (const float*)d_in[3];
    const float* Wr = (const float*)d_in[4];
    float* agg = (float*)d_out;  // d_out doubles as the f32 agg buffer
    u32* deg = (u32*)d_ws;       // 200 KB in ws

    hipMemsetAsync(d_out, 0, (size_t)NNODES * DD * sizeof(float), stream);
    hipMemsetAsync(d_ws, 0, (size_t)NNODES * sizeof(u32), stream);
    scatter_k<<<(NEDGES * 64) / 256, 256, 0, stream>>>(x, ei, agg, deg);
    lin_l_k<<<1024, 256, 0, stream>>>(agg, deg, Wl, bl);
    lin_r_k<<<1024, 256, 0, stream>>>(agg, x, Wr);
}

// Round 3
// 478.885 us; speedup vs baseline: 1.8520x; 1.8520x over previous
//
#include <hip/hip_runtime.h>
#include <hip/hip_bf16.h>

#define NNODES 50000
#define NEDGES 800000
#define DD 128

typedef unsigned int u32;
typedef unsigned short u16;

__device__ __forceinline__ u16 f2b(float f) {
    u32 u = __float_as_uint(f);
    u32 rounding = 0x7fffu + ((u >> 16) & 1u);
    return (u16)((u + rounding) >> 16);
}

// ---------------------------------------------------------------------------
// CSR path kernel 1: in-degree histogram.
// ---------------------------------------------------------------------------
__global__ __launch_bounds__(256) void hist_k(
    const int* __restrict__ ei, u32* __restrict__ deg) {
    u32 e = blockIdx.x * 256u + threadIdx.x;
    if (e >= NEDGES) return;
    atomicAdd(deg + ei[NEDGES + e], 1u);
}

// ---------------------------------------------------------------------------
// CSR path kernel 2: single-block exclusive scan of deg -> row_ptr, cursor.
// 1024 threads x 49 sequential elements + Hillis-Steele LDS scan.
// ---------------------------------------------------------------------------
__global__ __launch_bounds__(1024) void scan_k(
    const u32* __restrict__ deg, u32* __restrict__ row_ptr,
    u32* __restrict__ cursor) {
    __shared__ u32 sums[1024];
    const int tid = threadIdx.x;
    const int per = (NNODES + 1023) / 1024;  // 49
    const int start = tid * per;
    const int stop = min(start + per, NNODES);
    u32 s = 0;
    for (int i = start; i < stop; ++i) s += deg[i];
    sums[tid] = s;
    __syncthreads();
    for (int off = 1; off < 1024; off <<= 1) {
        u32 v = (tid >= off) ? sums[tid - off] : 0u;
        __syncthreads();
        sums[tid] += v;
        __syncthreads();
    }
    u32 run = (tid == 0) ? 0u : sums[tid - 1];
    for (int i = start; i < stop; ++i) {
        row_ptr[i] = run;
        cursor[i] = run;
        run += deg[i];
    }
}

// ---------------------------------------------------------------------------
// CSR path kernel 3: fill neighbor lists (src ids) ordered by dst.
// ---------------------------------------------------------------------------
__global__ __launch_bounds__(256) void fill_k(
    const int* __restrict__ ei, u32* __restrict__ cursor,
    u32* __restrict__ csr) {
    u32 e = blockIdx.x * 256u + threadIdx.x;
    if (e >= NEDGES) return;
    int dst = ei[NEDGES + e];
    u32 pos = atomicAdd(cursor + dst, 1u);
    csr[pos] = (u32)ei[e];
}

// ---------------------------------------------------------------------------
// CSR path kernel 4: gather-mean. One wave per node; lane = float2 pair.
// Pure reads (x rows coalesced 512B) — no atomics, agg written exactly once.
// ---------------------------------------------------------------------------
__global__ __launch_bounds__(256) void gather_k(
    const float* __restrict__ x, const u32* __restrict__ csr,
    const u32* __restrict__ row_ptr, const u32* __restrict__ deg,
    float* __restrict__ agg) {
    u32 gid = blockIdx.x * 256u + threadIdx.x;
    u32 node = gid >> 6;
    u32 lane = gid & 63u;
    if (node >= NNODES) return;
    u32 d = deg[node];
    u32 beg = row_ptr[node], end = beg + d;
    float2 acc = make_float2(0.f, 0.f);
    for (u32 i = beg; i < end; ++i) {
        u32 s = csr[i];  // wave-uniform
        float2 v = ((const float2*)(x + (size_t)s * DD))[lane];
        acc.x += v.x;
        acc.y += v.y;
    }
    float inv = 1.0f / fmaxf((float)d, 1.0f);
    ((float2*)(agg + (size_t)node * DD))[lane] =
        make_float2(acc.x * inv, acc.y * inv);
}

// ---------------------------------------------------------------------------
// Fallback (small ws): atomic scatter, as in R2.
// ---------------------------------------------------------------------------
__global__ __launch_bounds__(256) void scatter_k(
    const float* __restrict__ x, const int* __restrict__ ei,
    float* __restrict__ agg, u32* __restrict__ deg) {
    u32 gid = blockIdx.x * 256u + threadIdx.x;
    u32 edge = gid >> 6;
    u32 lane = gid & 63u;
    if (edge >= NEDGES) return;
    int src = ei[edge];
    int dst = ei[NEDGES + edge];
    float2 v = ((const float2*)(x + (size_t)src * DD))[lane];
    float* p = agg + (size_t)dst * DD + lane * 2u;
    unsafeAtomicAdd(p, v.x);
    unsafeAtomicAdd(p + 1, v.y);
    if (lane == 0) atomicAdd(deg + dst, 1u);
}

__global__ __launch_bounds__(256) void mean_k(
    float* __restrict__ agg, const u32* __restrict__ deg) {
    u32 gid = blockIdx.x * 256u + threadIdx.x;
    u32 node = gid >> 6;
    u32 lane = gid & 63u;
    if (node >= NNODES) return;
    float inv = 1.0f / fmaxf((float)deg[node], 1.0f);
    float2* p = (float2*)(agg + (size_t)node * DD) + lane;
    float2 v = *p;
    *p = make_float2(v.x * inv, v.y * inv);
}

// ---------------------------------------------------------------------------
// Phase 2: tmp = agg_mean @ W_l^T + b_l, IN PLACE over agg (= d_out).
// ---------------------------------------------------------------------------
__global__ __launch_bounds__(256) void lin_l_k(
    float* __restrict__ agg,
    const float* __restrict__ Wl, const float* __restrict__ bl) {
    __shared__ u32 WT[DD * 65];
    __shared__ float rows[4 * DD];
    __shared__ float sbias[DD];
    const int tid = threadIdx.x;
    {
        u16* WTs = (u16*)WT;
        for (int i = tid; i < DD * DD; i += 256) {
            int o = i >> 7, k = i & 127;
            WTs[k * 130 + o] = f2b(Wl[i]);
        }
        if (tid < DD) sbias[tid] = bl[tid];
    }
    __syncthreads();
    const int h = tid & 63;
    const int nl = tid >> 6;
    const int n_stage = tid >> 6, c_stage = tid & 63;
    for (int base = blockIdx.x * 4; base < NNODES; base += gridDim.x * 4) {
        ((float2*)rows)[tid] =
            ((const float2*)(agg + (size_t)(base + n_stage) * DD))[c_stage];
        __syncthreads();
        float acc0 = sbias[2 * h], acc1 = sbias[2 * h + 1];
#pragma unroll
        for (int k = 0; k < DD; ++k) {
            float a = rows[nl * DD + k];
            u32 w2 = WT[k * 65 + h];
            acc0 = fmaf(a, __uint_as_float(w2 << 16), acc0);
            acc1 = fmaf(a, __uint_as_float(w2 & 0xffff0000u), acc1);
        }
        __syncthreads();
        ((float2*)(agg + (size_t)(base + nl) * DD))[h] = make_float2(acc0, acc1);
    }
}

// ---------------------------------------------------------------------------
// Phase 3: out = relu(tmp + x @ W_r^T), IN PLACE over tmp (= d_out).
// ---------------------------------------------------------------------------
__global__ __launch_bounds__(256) void lin_r_k(
    float* __restrict__ io, const float* __restrict__ x,
    const float* __restrict__ Wr) {
    __shared__ u32 WT[DD * 65];
    __shared__ float rows[4 * DD];
    const int tid = threadIdx.x;
    {
        u16* WTs = (u16*)WT;
        for (int i = tid; i < DD * DD; i += 256) {
            int o = i >> 7, k = i & 127;
            WTs[k * 130 + o] = f2b(Wr[i]);
        }
    }
    __syncthreads();
    const int h = tid & 63;
    const int nl = tid >> 6;
    const int n_stage = tid >> 6, c_stage = tid & 63;
    for (int base = blockIdx.x * 4; base < NNODES; base += gridDim.x * 4) {
        ((float2*)rows)[tid] =
            ((const float2*)(x + (size_t)(base + n_stage) * DD))[c_stage];
        __syncthreads();
        float2 t2 = ((const float2*)(io + (size_t)(base + nl) * DD))[h];
        float acc0 = t2.x, acc1 = t2.y;
#pragma unroll
        for (int k = 0; k < DD; ++k) {
            float a = rows[nl * DD + k];
            u32 w2 = WT[k * 65 + h];
            acc0 = fmaf(a, __uint_as_float(w2 << 16), acc0);
            acc1 = fmaf(a, __uint_as_float(w2 & 0xffff0000u), acc1);
        }
        acc0 = fmaxf(acc0, 0.f);
        acc1 = fmaxf(acc1, 0.f);
        __syncthreads();
        ((float2*)(io + (size_t)(base + nl) * DD))[h] = make_float2(acc0, acc1);
    }
}

extern "C" void kernel_launch(void* const* d_in, const int* in_sizes, int n_in,
                              void* d_out, int out_size, void* d_ws, size_t ws_size,
                              hipStream_t stream) {
    const float* x  = (const float*)d_in[0];
    const int*   ei = (const int*)d_in[1];
    const float* Wl = (const float*)d_in[2];
    const float* bl = (const float*)d_in[3];
    const float* Wr = (const float*)d_in[4];
    float* agg = (float*)d_out;  // d_out doubles as the f32 agg buffer

    const size_t need = ((size_t)3 * NNODES + NEDGES) * sizeof(u32);
    if (ws_size >= need) {
        // CSR gather path (no f32 atomics)
        u32* deg     = (u32*)d_ws;
        u32* row_ptr = deg + NNODES;
        u32* cursor  = row_ptr + NNODES;
        u32* csr     = cursor + NNODES;
        hipMemsetAsync(deg, 0, (size_t)NNODES * sizeof(u32), stream);
        hist_k<<<(NEDGES + 255) / 256, 256, 0, stream>>>(ei, deg);
        scan_k<<<1, 1024, 0, stream>>>(deg, row_ptr, cursor);
        fill_k<<<(NEDGES + 255) / 256, 256, 0, stream>>>(ei, cursor, csr);
        gather_k<<<(NNODES * 64 + 255) / 256, 256, 0, stream>>>(
            x, csr, row_ptr, deg, agg);
    } else {
        // Fallback: atomic scatter
        u32* deg = (u32*)d_ws;
        hipMemsetAsync(d_out, 0, (size_t)NNODES * DD * sizeof(float), stream);
        hipMemsetAsync(d_ws, 0, (size_t)NNODES * sizeof(u32), stream);
        scatter_k<<<(NEDGES * 64) / 256, 256, 0, stream>>>(x, ei, agg, deg);
        mean_k<<<(NNODES * 64 + 255) / 256, 256, 0, stream>>>(agg, deg);
    }
    lin_l_k<<<1024, 256, 0, stream>>>(agg, Wl, bl);
    lin_r_k<<<1024, 256, 0, stream>>>(agg, x, Wr);
}

// Round 4
// 323.490 us; speedup vs baseline: 2.7416x; 1.4804x over previous
//
#include <hip/hip_runtime.h>
#include <hip/hip_bf16.h>

#define NNODES 50000
#define NEDGES 800000
#define DD 128
#define SCAN_B 196  // ceil(50000/256)

typedef unsigned int u32;
typedef unsigned short u16;

__device__ __forceinline__ u16 f2b(float f) {
    u32 u = __float_as_uint(f);
    u32 rounding = 0x7fffu + ((u >> 16) & 1u);
    return (u16)((u + rounding) >> 16);
}

// ---------------------------------------------------------------------------
// Prep A: pack [Wl;Wr] into bf16-pair planes: wtg[p*8192 + k*64 + h] =
// pack(W[2h][k], W[2h+1][k]), p=0 -> Wl, p=1 -> Wr.
// ---------------------------------------------------------------------------
__global__ __launch_bounds__(256) void prep_wt_k(
    const float* __restrict__ Wl, const float* __restrict__ Wr,
    u32* __restrict__ wtg) {
    int idx = blockIdx.x * 256 + threadIdx.x;
    if (idx >= 16384) return;
    int p = idx >> 13, rem = idx & 8191, k = rem >> 6, h = rem & 63;
    const float* W = p ? Wr : Wl;
    u32 lo = f2b(W[(2 * h) * DD + k]);
    u32 hi = f2b(W[(2 * h + 1) * DD + k]);
    wtg[idx] = lo | (hi << 16);
}

// ---------------------------------------------------------------------------
// Prep B: x -> packed bf16 rows (halves gather traffic).
// ---------------------------------------------------------------------------
__global__ __launch_bounds__(256) void xconv_k(
    const float* __restrict__ x, u32* __restrict__ xb) {
    int i = blockIdx.x * 256 + threadIdx.x;  // 50000*64 exactly
    float2 v = ((const float2*)x)[i];
    xb[i] = (u32)f2b(v.x) | ((u32)f2b(v.y) << 16);
}

// ---------------------------------------------------------------------------
// CSR build: histogram -> hierarchical scan (3 kernels) -> fill.
// ---------------------------------------------------------------------------
__global__ __launch_bounds__(256) void hist_k(
    const int* __restrict__ ei, u32* __restrict__ deg) {
    u32 e = blockIdx.x * 256u + threadIdx.x;
    if (e >= NEDGES) return;
    atomicAdd(deg + ei[NEDGES + e], 1u);
}

__global__ __launch_bounds__(256) void scan1_k(
    const u32* __restrict__ deg, u32* __restrict__ part) {
    __shared__ u32 s[256];
    int i = blockIdx.x * 256 + threadIdx.x;
    int t = threadIdx.x;
    s[t] = (i < NNODES) ? deg[i] : 0u;
    __syncthreads();
    for (int off = 128; off > 0; off >>= 1) {
        if (t < off) s[t] += s[t + off];
        __syncthreads();
    }
    if (t == 0) part[blockIdx.x] = s[0];
}

__global__ __launch_bounds__(256) void scan2_k(u32* __restrict__ part) {
    __shared__ u32 s[256];
    int t = threadIdx.x;
    u32 v = (t < SCAN_B) ? part[t] : 0u;
    s[t] = v;
    __syncthreads();
    for (int off = 1; off < 256; off <<= 1) {
        u32 a = (t >= off) ? s[t - off] : 0u;
        __syncthreads();
        s[t] += a;
        __syncthreads();
    }
    if (t < SCAN_B) part[t] = s[t] - v;  // exclusive
}

__global__ __launch_bounds__(256) void scan3_k(
    const u32* __restrict__ deg, const u32* __restrict__ part,
    u32* __restrict__ row_ptr, u32* __restrict__ cursor) {
    __shared__ u32 s[256];
    int i = blockIdx.x * 256 + threadIdx.x;
    int t = threadIdx.x;
    u32 v = (i < NNODES) ? deg[i] : 0u;
    s[t] = v;
    __syncthreads();
    for (int off = 1; off < 256; off <<= 1) {
        u32 a = (t >= off) ? s[t - off] : 0u;
        __syncthreads();
        s[t] += a;
        __syncthreads();
    }
    if (i < NNODES) {
        u32 e = part[blockIdx.x] + s[t] - v;
        row_ptr[i] = e;
        cursor[i] = e;
    }
}

__global__ __launch_bounds__(256) void fill_k(
    const int* __restrict__ ei, u32* __restrict__ cursor,
    u32* __restrict__ csr) {
    u32 e = blockIdx.x * 256u + threadIdx.x;
    if (e >= NEDGES) return;
    int dst = ei[NEDGES + e];
    u32 pos = atomicAdd(cursor + dst, 1u);
    csr[pos] = (u32)ei[e];
}

// ---------------------------------------------------------------------------
// Gather-mean from packed-bf16 x. One wave per node; lane = bf16 pair (u32).
// ---------------------------------------------------------------------------
__global__ __launch_bounds__(256) void gatherb_k(
    const u32* __restrict__ xb, const u32* __restrict__ csr,
    const u32* __restrict__ row_ptr, const u32* __restrict__ deg,
    float* __restrict__ agg) {
    u32 gid = blockIdx.x * 256u + threadIdx.x;
    u32 node = gid >> 6;
    u32 lane = gid & 63u;
    if (node >= NNODES) return;
    u32 d = deg[node];
    u32 beg = row_ptr[node], end = beg + d;
    float a0 = 0.f, a1 = 0.f;
    for (u32 i = beg; i < end; ++i) {
        u32 s = csr[i];  // wave-uniform
        u32 v = xb[(size_t)s * 64 + lane];
        a0 += __uint_as_float(v << 16);
        a1 += __uint_as_float(v & 0xffff0000u);
    }
    float inv = 1.0f / fmaxf((float)d, 1.0f);
    ((float2*)(agg + (size_t)node * DD))[lane] = make_float2(a0 * inv, a1 * inv);
}

// f32 gather for the mid-sized-ws path
__global__ __launch_bounds__(256) void gather_k(
    const float* __restrict__ x, const u32* __restrict__ csr,
    const u32* __restrict__ row_ptr, const u32* __restrict__ deg,
    float* __restrict__ agg) {
    u32 gid = blockIdx.x * 256u + threadIdx.x;
    u32 node = gid >> 6;
    u32 lane = gid & 63u;
    if (node >= NNODES) return;
    u32 d = deg[node];
    u32 beg = row_ptr[node], end = beg + d;
    float2 acc = make_float2(0.f, 0.f);
    for (u32 i = beg; i < end; ++i) {
        u32 s = csr[i];
        float2 v = ((const float2*)(x + (size_t)s * DD))[lane];
        acc.x += v.x;
        acc.y += v.y;
    }
    float inv = 1.0f / fmaxf((float)d, 1.0f);
    ((float2*)(agg + (size_t)node * DD))[lane] =
        make_float2(acc.x * inv, acc.y * inv);
}

// ---------------------------------------------------------------------------
// Fused dual-GEMM: out = relu(agg @ Wl^T + b + x @ Wr^T), in place over agg.
// Block = 64 nodes x 128 outputs; thread = 4 nodes x 8 outputs (32 accums).
// All LDS traffic is b128; rows pitch 132 -> 2-way conflicts only (free).
// ---------------------------------------------------------------------------
__global__ __launch_bounds__(256) void fused_k(
    const float* __restrict__ agg, const float* __restrict__ x,
    const u32* __restrict__ wtg, const float* __restrict__ bl,
    float* __restrict__ out) {
    __shared__ float rows[64 * 132];
    __shared__ u32 wt[128 * 64];
    __shared__ float sbias[DD];
    const int tid = threadIdx.x;
    if (tid < DD) sbias[tid] = bl[tid];
    const int og = tid & 15, ng = tid >> 4;
    const int h0 = og * 4;  // base u32-pair -> outputs o0..o0+7
    const int o0 = og * 8;
    const int n0 = ng * 4;
    const int base = blockIdx.x * 64;
    const int kq = tid & 31;  // float4 column for staging
    const int rl = tid >> 5;  // staging row 0..7

    float acc[4][8];
#pragma unroll
    for (int i = 0; i < 4; ++i)
#pragma unroll
        for (int j = 0; j < 8; ++j) acc[i][j] = 0.f;

    for (int p = 0; p < 2; ++p) {
        const float* A = p ? x : agg;
        // stage 64 node rows (f32, pitch 132)
        for (int rr = 0; rr < 64; rr += 8) {
            int n = base + rr + rl;
            n = n < NNODES ? n : NNODES - 1;
            float4 v = ((const float4*)A)[(size_t)n * 32 + kq];
            *((float4*)&rows[(rr + rl) * 132 + kq * 4]) = v;
        }
        // stage weight plane p (bf16 pairs, [k][h], 32 KB)
        {
            const uint4* s4 = (const uint4*)(wtg + p * 8192);
            uint4* d4 = (uint4*)wt;
#pragma unroll
            for (int j = 0; j < 8; ++j) d4[tid + j * 256] = s4[tid + j * 256];
        }
        __syncthreads();
#pragma unroll 2
        for (int k = 0; k < DD; k += 4) {
            float4 a0 = *(const float4*)&rows[(n0 + 0) * 132 + k];
            float4 a1 = *(const float4*)&rows[(n0 + 1) * 132 + k];
            float4 a2 = *(const float4*)&rows[(n0 + 2) * 132 + k];
            float4 a3 = *(const float4*)&rows[(n0 + 3) * 132 + k];
#pragma unroll
            for (int j = 0; j < 4; ++j) {
                uint4 wv = *(const uint4*)&wt[(k + j) * 64 + h0];
                float aj0 = ((const float*)&a0)[j];
                float aj1 = ((const float*)&a1)[j];
                float aj2 = ((const float*)&a2)[j];
                float aj3 = ((const float*)&a3)[j];
#pragma unroll
                for (int hh = 0; hh < 4; ++hh) {
                    u32 w2 = ((const u32*)&wv)[hh];
                    float we = __uint_as_float(w2 << 16);
                    float wo = __uint_as_float(w2 & 0xffff0000u);
                    acc[0][2 * hh] = fmaf(aj0, we, acc[0][2 * hh]);
                    acc[0][2 * hh + 1] = fmaf(aj0, wo, acc[0][2 * hh + 1]);
                    acc[1][2 * hh] = fmaf(aj1, we, acc[1][2 * hh]);
                    acc[1][2 * hh + 1] = fmaf(aj1, wo, acc[1][2 * hh + 1]);
                    acc[2][2 * hh] = fmaf(aj2, we, acc[2][2 * hh]);
                    acc[2][2 * hh + 1] = fmaf(aj2, wo, acc[2][2 * hh + 1]);
                    acc[3][2 * hh] = fmaf(aj3, we, acc[3][2 * hh]);
                    acc[3][2 * hh + 1] = fmaf(aj3, wo, acc[3][2 * hh + 1]);
                }
            }
        }
        __syncthreads();
    }
#pragma unroll
    for (int i = 0; i < 4; ++i) {
        int n = base + n0 + i;
        if (n < NNODES) {
            float4 r0, r1;
            r0.x = fmaxf(acc[i][0] + sbias[o0 + 0], 0.f);
            r0.y = fmaxf(acc[i][1] + sbias[o0 + 1], 0.f);
            r0.z = fmaxf(acc[i][2] + sbias[o0 + 2], 0.f);
            r0.w = fmaxf(acc[i][3] + sbias[o0 + 3], 0.f);
            r1.x = fmaxf(acc[i][4] + sbias[o0 + 4], 0.f);
            r1.y = fmaxf(acc[i][5] + sbias[o0 + 5], 0.f);
            r1.z = fmaxf(acc[i][6] + sbias[o0 + 6], 0.f);
            r1.w = fmaxf(acc[i][7] + sbias[o0 + 7], 0.f);
            *((float4*)&out[(size_t)n * DD + o0]) = r0;
            *((float4*)&out[(size_t)n * DD + o0 + 4]) = r1;
        }
    }
}

// ---------------------------------------------------------------------------
// Small-ws fallbacks (R2 path)
// ---------------------------------------------------------------------------
__global__ __launch_bounds__(256) void scatter_k(
    const float* __restrict__ x, const int* __restrict__ ei,
    float* __restrict__ agg, u32* __restrict__ deg) {
    u32 gid = blockIdx.x * 256u + threadIdx.x;
    u32 edge = gid >> 6;
    u32 lane = gid & 63u;
    if (edge >= NEDGES) return;
    int src = ei[edge];
    int dst = ei[NEDGES + edge];
    float2 v = ((const float2*)(x + (size_t)src * DD))[lane];
    float* p = agg + (size_t)dst * DD + lane * 2u;
    unsafeAtomicAdd(p, v.x);
    unsafeAtomicAdd(p + 1, v.y);
    if (lane == 0) atomicAdd(deg + dst, 1u);
}

__global__ __launch_bounds__(256) void mean_k(
    float* __restrict__ agg, const u32* __restrict__ deg) {
    u32 gid = blockIdx.x * 256u + threadIdx.x;
    u32 node = gid >> 6;
    u32 lane = gid & 63u;
    if (node >= NNODES) return;
    float inv = 1.0f / fmaxf((float)deg[node], 1.0f);
    float2* p = (float2*)(agg + (size_t)node * DD) + lane;
    float2 v = *p;
    *p = make_float2(v.x * inv, v.y * inv);
}

__global__ __launch_bounds__(256) void lin_l_k(
    float* __restrict__ agg,
    const float* __restrict__ Wl, const float* __restrict__ bl) {
    __shared__ u32 WT[DD * 65];
    __shared__ float rows[4 * DD];
    __shared__ float sbias[DD];
    const int tid = threadIdx.x;
    {
        u16* WTs = (u16*)WT;
        for (int i = tid; i < DD * DD; i += 256) {
            int o = i >> 7, k = i & 127;
            WTs[k * 130 + o] = f2b(Wl[i]);
        }
        if (tid < DD) sbias[tid] = bl[tid];
    }
    __syncthreads();
    const int h = tid & 63;
    const int nl = tid >> 6;
    for (int base = blockIdx.x * 4; base < NNODES; base += gridDim.x * 4) {
        ((float2*)rows)[tid] =
            ((const float2*)(agg + (size_t)(base + (tid >> 6)) * DD))[tid & 63];
        __syncthreads();
        float acc0 = sbias[2 * h], acc1 = sbias[2 * h + 1];
#pragma unroll
        for (int k = 0; k < DD; ++k) {
            float a = rows[nl * DD + k];
            u32 w2 = WT[k * 65 + h];
            acc0 = fmaf(a, __uint_as_float(w2 << 16), acc0);
            acc1 = fmaf(a, __uint_as_float(w2 & 0xffff0000u), acc1);
        }
        __syncthreads();
        ((float2*)(agg + (size_t)(base + nl) * DD))[h] = make_float2(acc0, acc1);
    }
}

__global__ __launch_bounds__(256) void lin_r_k(
    float* __restrict__ io, const float* __restrict__ x,
    const float* __restrict__ Wr) {
    __shared__ u32 WT[DD * 65];
    __shared__ float rows[4 * DD];
    const int tid = threadIdx.x;
    {
        u16* WTs = (u16*)WT;
        for (int i = tid; i < DD * DD; i += 256) {
            int o = i >> 7, k = i & 127;
            WTs[k * 130 + o] = f2b(Wr[i]);
        }
    }
    __syncthreads();
    const int h = tid & 63;
    const int nl = tid >> 6;
    for (int base = blockIdx.x * 4; base < NNODES; base += gridDim.x * 4) {
        ((float2*)rows)[tid] =
            ((const float2*)(x + (size_t)(base + (tid >> 6)) * DD))[tid & 63];
        __syncthreads();
        float2 t2 = ((const float2*)(io + (size_t)(base + nl) * DD))[h];
        float acc0 = t2.x, acc1 = t2.y;
#pragma unroll
        for (int k = 0; k < DD; ++k) {
            float a = rows[nl * DD + k];
            u32 w2 = WT[k * 65 + h];
            acc0 = fmaf(a, __uint_as_float(w2 << 16), acc0);
            acc1 = fmaf(a, __uint_as_float(w2 & 0xffff0000u), acc1);
        }
        acc0 = fmaxf(acc0, 0.f);
        acc1 = fmaxf(acc1, 0.f);
        __syncthreads();
        ((float2*)(io + (size_t)(base + nl) * DD))[h] = make_float2(acc0, acc1);
    }
}

extern "C" void kernel_launch(void* const* d_in, const int* in_sizes, int n_in,
                              void* d_out, int out_size, void* d_ws, size_t ws_size,
                              hipStream_t stream) {
    const float* x  = (const float*)d_in[0];
    const int*   ei = (const int*)d_in[1];
    const float* Wl = (const float*)d_in[2];
    const float* bl = (const float*)d_in[3];
    const float* Wr = (const float*)d_in[4];
    float* agg = (float*)d_out;  // d_out doubles as the f32 agg buffer

    // ws layout: deg | row_ptr | cursor | csr | part | wtg | xb
    u32* deg     = (u32*)d_ws;
    u32* row_ptr = deg + NNODES;
    u32* cursor  = row_ptr + NNODES;
    u32* csr     = cursor + NNODES;
    u32* part    = csr + NEDGES;
    u32* wtg     = part + 256;
    u32* xb      = wtg + 16384;
    const size_t need_mid  = ((size_t)(3 * NNODES + NEDGES + 256 + 16384)) * 4;
    const size_t need_full = need_mid + (size_t)NNODES * 64 * 4;

    if (ws_size >= need_mid) {
        hipMemsetAsync(deg, 0, (size_t)NNODES * sizeof(u32), stream);
        prep_wt_k<<<64, 256, 0, stream>>>(Wl, Wr, wtg);
        if (ws_size >= need_full)
            xconv_k<<<12500, 256, 0, stream>>>(x, xb);
        hist_k<<<3125, 256, 0, stream>>>(ei, deg);
        scan1_k<<<SCAN_B, 256, 0, stream>>>(deg, part);
        scan2_k<<<1, 256, 0, stream>>>(part);
        scan3_k<<<SCAN_B, 256, 0, stream>>>(deg, part, row_ptr, cursor);
        fill_k<<<3125, 256, 0, stream>>>(ei, cursor, csr);
        if (ws_size >= need_full)
            gatherb_k<<<12500, 256, 0, stream>>>(xb, csr, row_ptr, deg, agg);
        else
            gather_k<<<12500, 256, 0, stream>>>(x, csr, row_ptr, deg, agg);
        fused_k<<<(NNODES + 63) / 64, 256, 0, stream>>>(agg, x, wtg, bl, agg);
    } else {
        hipMemsetAsync(d_out, 0, (size_t)NNODES * DD * sizeof(float), stream);
        hipMemsetAsync(d_ws, 0, (size_t)NNODES * sizeof(u32), stream);
        scatter_k<<<(NEDGES * 64) / 256, 256, 0, stream>>>(x, ei, agg, deg);
        mean_k<<<(NNODES * 64 + 255) / 256, 256, 0, stream>>>(agg, deg);
        lin_l_k<<<1024, 256, 0, stream>>>(agg, Wl, bl);
        lin_r_k<<<1024, 256, 0, stream>>>(agg, x, Wr);
    }
}

// Round 5
// 230.057 us; speedup vs baseline: 3.8550x; 1.4061x over previous
//
#include <hip/hip_runtime.h>
#include <hip/hip_bf16.h>

#define NNODES 50000
#define NEDGES 800000
#define DD 128
#define SCAN_B 196  // ceil(50000/256)
#define WPITCH 129  // dwords per W row in LDS (odd -> bank hop 1)

typedef unsigned int u32;
typedef unsigned short u16;
typedef short bf16x8 __attribute__((ext_vector_type(8)));
typedef float f32x4 __attribute__((ext_vector_type(4)));

union U4B8 {
    uint4 u;
    bf16x8 b;
};

__device__ __forceinline__ u16 f2b(float f) {
    u32 u = __float_as_uint(f);
    u32 rounding = 0x7fffu + ((u >> 16) & 1u);
    return (u16)((u + rounding) >> 16);
}

// ---------------------------------------------------------------------------
// Prep A: Wb[o][k] bf16 pairs, o=0..127, k=0..255 (k<128 -> Wl, k>=128 -> Wr).
// wb is [128][128] u32 (each u32 = 2 consecutive-k bf16).
// ---------------------------------------------------------------------------
__global__ __launch_bounds__(256) void prep_wb_k(
    const float* __restrict__ Wl, const float* __restrict__ Wr,
    u32* __restrict__ wb) {
    int idx = blockIdx.x * 256 + threadIdx.x;
    if (idx >= 16384) return;
    int o = idx >> 7, c = idx & 127;  // c = k-pair index, k0=2c
    int k0 = 2 * c;
    const float* src = (k0 < DD) ? (Wl + o * DD + k0) : (Wr + o * DD + (k0 - DD));
    u32 lo = f2b(src[0]);
    u32 hi = f2b(src[1]);
    wb[idx] = lo | (hi << 16);
}

// ---------------------------------------------------------------------------
// Prep B: x -> packed bf16 rows (halves gather traffic, feeds MFMA).
// ---------------------------------------------------------------------------
__global__ __launch_bounds__(256) void xconv_k(
    const float* __restrict__ x, u32* __restrict__ xb) {
    int i = blockIdx.x * 256 + threadIdx.x;  // 50000*64 exactly
    float2 v = ((const float2*)x)[i];
    xb[i] = (u32)f2b(v.x) | ((u32)f2b(v.y) << 16);
}

// ---------------------------------------------------------------------------
// CSR build: histogram -> hierarchical scan (3 kernels) -> fill.
// ---------------------------------------------------------------------------
__global__ __launch_bounds__(256) void hist_k(
    const int* __restrict__ ei, u32* __restrict__ deg) {
    u32 e = blockIdx.x * 256u + threadIdx.x;
    if (e >= NEDGES) return;
    atomicAdd(deg + ei[NEDGES + e], 1u);
}

__global__ __launch_bounds__(256) void scan1_k(
    const u32* __restrict__ deg, u32* __restrict__ part) {
    __shared__ u32 s[256];
    int i = blockIdx.x * 256 + threadIdx.x;
    int t = threadIdx.x;
    s[t] = (i < NNODES) ? deg[i] : 0u;
    __syncthreads();
    for (int off = 128; off > 0; off >>= 1) {
        if (t < off) s[t] += s[t + off];
        __syncthreads();
    }
    if (t == 0) part[blockIdx.x] = s[0];
}

__global__ __launch_bounds__(256) void scan2_k(u32* __restrict__ part) {
    __shared__ u32 s[256];
    int t = threadIdx.x;
    u32 v = (t < SCAN_B) ? part[t] : 0u;
    s[t] = v;
    __syncthreads();
    for (int off = 1; off < 256; off <<= 1) {
        u32 a = (t >= off) ? s[t - off] : 0u;
        __syncthreads();
        s[t] += a;
        __syncthreads();
    }
    if (t < SCAN_B) part[t] = s[t] - v;  // exclusive
}

__global__ __launch_bounds__(256) void scan3_k(
    const u32* __restrict__ deg, const u32* __restrict__ part,
    u32* __restrict__ row_ptr, u32* __restrict__ cursor) {
    __shared__ u32 s[256];
    int i = blockIdx.x * 256 + threadIdx.x;
    int t = threadIdx.x;
    u32 v = (i < NNODES) ? deg[i] : 0u;
    s[t] = v;
    __syncthreads();
    for (int off = 1; off < 256; off <<= 1) {
        u32 a = (t >= off) ? s[t - off] : 0u;
        __syncthreads();
        s[t] += a;
        __syncthreads();
    }
    if (i < NNODES) {
        u32 e = part[blockIdx.x] + s[t] - v;
        row_ptr[i] = e;
        cursor[i] = e;
    }
}

__global__ __launch_bounds__(256) void fill_k(
    const int* __restrict__ ei, u32* __restrict__ cursor,
    u32* __restrict__ csr) {
    u32 e = blockIdx.x * 256u + threadIdx.x;
    if (e >= NEDGES) return;
    int dst = ei[NEDGES + e];
    u32 pos = atomicAdd(cursor + dst, 1u);
    csr[pos] = (u32)ei[e];
}

// ---------------------------------------------------------------------------
// Gather-mean, de-serialized: lanes cooperatively read up to 64 csr entries
// (one coalesced load), __shfl-broadcast each; inner loop unrolled x4 so 4
// independent xb row-loads are in flight. Writes f32 agg rows (= d_out).
// ---------------------------------------------------------------------------
__global__ __launch_bounds__(256) void gatherb2_k(
    const u32* __restrict__ xb, const u32* __restrict__ csr,
    const u32* __restrict__ row_ptr, const u32* __restrict__ deg,
    float* __restrict__ agg) {
    u32 gid = blockIdx.x * 256u + threadIdx.x;
    u32 node = gid >> 6;
    u32 lane = gid & 63u;
    if (node >= NNODES) return;
    u32 d = deg[node];
    u32 beg = row_ptr[node], end = beg + d;
    float a0 = 0.f, a1 = 0.f;
    for (u32 i = beg; i < end; i += 64u) {
        u32 cnt = min(64u, end - i);
        u32 idx = i + lane;
        u32 sv = csr[idx < end ? idx : (end - 1)];  // coalesced block read
        u32 j = 0;
        for (; j + 4 <= cnt; j += 4) {
            u32 s0 = __shfl(sv, (int)(j + 0), 64);
            u32 s1 = __shfl(sv, (int)(j + 1), 64);
            u32 s2 = __shfl(sv, (int)(j + 2), 64);
            u32 s3 = __shfl(sv, (int)(j + 3), 64);
            u32 v0 = xb[(size_t)s0 * 64 + lane];
            u32 v1 = xb[(size_t)s1 * 64 + lane];
            u32 v2 = xb[(size_t)s2 * 64 + lane];
            u32 v3 = xb[(size_t)s3 * 64 + lane];
            a0 += __uint_as_float(v0 << 16);
            a1 += __uint_as_float(v0 & 0xffff0000u);
            a0 += __uint_as_float(v1 << 16);
            a1 += __uint_as_float(v1 & 0xffff0000u);
            a0 += __uint_as_float(v2 << 16);
            a1 += __uint_as_float(v2 & 0xffff0000u);
            a0 += __uint_as_float(v3 << 16);
            a1 += __uint_as_float(v3 & 0xffff0000u);
        }
        for (; j < cnt; ++j) {
            u32 s = __shfl(sv, (int)j, 64);
            u32 v = xb[(size_t)s * 64 + lane];
            a0 += __uint_as_float(v << 16);
            a1 += __uint_as_float(v & 0xffff0000u);
        }
    }
    float inv = 1.0f / fmaxf((float)d, 1.0f);
    ((float2*)(agg + (size_t)node * DD))[lane] = make_float2(a0 * inv, a1 * inv);
}

// ---------------------------------------------------------------------------
// MFMA fused dual-GEMM: out = relu([agg|x]_bf16 @ [Wl;Wr]^T + b), in place
// over d_out. Block = 128 rows x 128 outs, 4 waves; wave = 32 rows (2 M-tiles
// of 16x16x32), 8 N-tiles, K = 256 (k<128 agg-f32->bf16, k>=128 xb).
// W in LDS: 128 rows x 129 dwords (odd pitch). A-frags straight from global.
// In-place safe: each wave reads only the 32 rows it later writes, and all
// A reads precede the epilogue stores.
// ---------------------------------------------------------------------------
__global__ __launch_bounds__(256) void mfma_fused_k(
    const float* __restrict__ agg, const u32* __restrict__ xb,
    const u32* __restrict__ wb, const float* __restrict__ bl,
    float* __restrict__ out) {
    __shared__ u32 w_lds[DD * WPITCH];
    __shared__ float sbias[DD];
    const int tid = threadIdx.x;
    // stage W: 128 rows x 128 u32 (512 B/row, 32 threads/row)
    for (int r = tid >> 5; r < DD; r += 8) {
        int c = (tid & 31) * 4;
        uint4 v = *(const uint4*)&wb[r * DD + c];
        *(uint4*)&w_lds[r * WPITCH + c] = v;
    }
    if (tid < DD) sbias[tid] = bl[tid];
    __syncthreads();

    const int wave = tid >> 6, lane = tid & 63;
    const int m = lane & 15, quad = lane >> 4;
    const int row0 = blockIdx.x * 128 + wave * 32;

    f32x4 acc[2][8];
#pragma unroll
    for (int t = 0; t < 2; ++t)
#pragma unroll
        for (int nt = 0; nt < 8; ++nt) acc[t][nt] = (f32x4){0.f, 0.f, 0.f, 0.f};

    for (int ks = 0; ks < 8; ++ks) {
        U4B8 af[2];
        if (ks < 4) {
            // A from agg (f32 rows of d_out), convert to bf16 in-register
#pragma unroll
            for (int t = 0; t < 2; ++t) {
                int r = row0 + t * 16 + m;
                r = r < NNODES ? r : NNODES - 1;
                const float* p = agg + (size_t)r * DD + ks * 32 + quad * 8;
                float4 lo = *(const float4*)p;
                float4 hi = *(const float4*)(p + 4);
                af[t].u.x = (u32)f2b(lo.x) | ((u32)f2b(lo.y) << 16);
                af[t].u.y = (u32)f2b(lo.z) | ((u32)f2b(lo.w) << 16);
                af[t].u.z = (u32)f2b(hi.x) | ((u32)f2b(hi.y) << 16);
                af[t].u.w = (u32)f2b(hi.z) | ((u32)f2b(hi.w) << 16);
            }
        } else {
            // A from xb (packed bf16)
#pragma unroll
            for (int t = 0; t < 2; ++t) {
                int r = row0 + t * 16 + m;
                r = r < NNODES ? r : NNODES - 1;
                af[t].u = *(const uint4*)&xb[(size_t)r * 64 + (ks - 4) * 16 + quad * 4];
            }
        }
#pragma unroll
        for (int nt = 0; nt < 8; ++nt) {
            U4B8 bf;
            bf.u = *(const uint4*)&w_lds[(nt * 16 + m) * WPITCH + ks * 16 + quad * 4];
            acc[0][nt] = __builtin_amdgcn_mfma_f32_16x16x32_bf16(
                af[0].b, bf.b, acc[0][nt], 0, 0, 0);
            acc[1][nt] = __builtin_amdgcn_mfma_f32_16x16x32_bf16(
                af[1].b, bf.b, acc[1][nt], 0, 0, 0);
        }
    }
    // epilogue: D row = quad*4 + reg, col = nt*16 + m
#pragma unroll
    for (int t = 0; t < 2; ++t) {
#pragma unroll
        for (int nt = 0; nt < 8; ++nt) {
            int col = nt * 16 + m;
            float b = sbias[col];
#pragma unroll
            for (int r = 0; r < 4; ++r) {
                int row = row0 + t * 16 + quad * 4 + r;
                if (row < NNODES)
                    out[(size_t)row * DD + col] = fmaxf(acc[t][nt][r] + b, 0.f);
            }
        }
    }
}

// ---------------------------------------------------------------------------
// Small-ws fallback (R2 path)
// ---------------------------------------------------------------------------
__global__ __launch_bounds__(256) void scatter_k(
    const float* __restrict__ x, const int* __restrict__ ei,
    float* __restrict__ agg, u32* __restrict__ deg) {
    u32 gid = blockIdx.x * 256u + threadIdx.x;
    u32 edge = gid >> 6;
    u32 lane = gid & 63u;
    if (edge >= NEDGES) return;
    int src = ei[edge];
    int dst = ei[NEDGES + edge];
    float2 v = ((const float2*)(x + (size_t)src * DD))[lane];
    float* p = agg + (size_t)dst * DD + lane * 2u;
    unsafeAtomicAdd(p, v.x);
    unsafeAtomicAdd(p + 1, v.y);
    if (lane == 0) atomicAdd(deg + dst, 1u);
}

__global__ __launch_bounds__(256) void mean_k(
    float* __restrict__ agg, const u32* __restrict__ deg) {
    u32 gid = blockIdx.x * 256u + threadIdx.x;
    u32 node = gid >> 6;
    u32 lane = gid & 63u;
    if (node >= NNODES) return;
    float inv = 1.0f / fmaxf((float)deg[node], 1.0f);
    float2* p = (float2*)(agg + (size_t)node * DD) + lane;
    float2 v = *p;
    *p = make_float2(v.x * inv, v.y * inv);
}

__global__ __launch_bounds__(256) void lin_l_k(
    float* __restrict__ agg,
    const float* __restrict__ Wl, const float* __restrict__ bl) {
    __shared__ u32 WT[DD * 65];
    __shared__ float rows[4 * DD];
    __shared__ float sbias[DD];
    const int tid = threadIdx.x;
    {
        u16* WTs = (u16*)WT;
        for (int i = tid; i < DD * DD; i += 256) {
            int o = i >> 7, k = i & 127;
            WTs[k * 130 + o] = f2b(Wl[i]);
        }
        if (tid < DD) sbias[tid] = bl[tid];
    }
    __syncthreads();
    const int h = tid & 63;
    const int nl = tid >> 6;
    for (int base = blockIdx.x * 4; base < NNODES; base += gridDim.x * 4) {
        ((float2*)rows)[tid] =
            ((const float2*)(agg + (size_t)(base + (tid >> 6)) * DD))[tid & 63];
        __syncthreads();
        float acc0 = sbias[2 * h], acc1 = sbias[2 * h + 1];
#pragma unroll
        for (int k = 0; k < DD; ++k) {
            float a = rows[nl * DD + k];
            u32 w2 = WT[k * 65 + h];
            acc0 = fmaf(a, __uint_as_float(w2 << 16), acc0);
            acc1 = fmaf(a, __uint_as_float(w2 & 0xffff0000u), acc1);
        }
        __syncthreads();
        ((float2*)(agg + (size_t)(base + nl) * DD))[h] = make_float2(acc0, acc1);
    }
}

__global__ __launch_bounds__(256) void lin_r_k(
    float* __restrict__ io, const float* __restrict__ x,
    const float* __restrict__ Wr) {
    __shared__ u32 WT[DD * 65];
    __shared__ float rows[4 * DD];
    const int tid = threadIdx.x;
    {
        u16* WTs = (u16*)WT;
        for (int i = tid; i < DD * DD; i += 256) {
            int o = i >> 7, k = i & 127;
            WTs[k * 130 + o] = f2b(Wr[i]);
        }
    }
    __syncthreads();
    const int h = tid & 63;
    const int nl = tid >> 6;
    for (int base = blockIdx.x * 4; base < NNODES; base += gridDim.x * 4) {
        ((float2*)rows)[tid] =
            ((const float2*)(x + (size_t)(base + (tid >> 6)) * DD))[tid & 63];
        __syncthreads();
        float2 t2 = ((const float2*)(io + (size_t)(base + nl) * DD))[h];
        float acc0 = t2.x, acc1 = t2.y;
#pragma unroll
        for (int k = 0; k < DD; ++k) {
            float a = rows[nl * DD + k];
            u32 w2 = WT[k * 65 + h];
            acc0 = fmaf(a, __uint_as_float(w2 << 16), acc0);
            acc1 = fmaf(a, __uint_as_float(w2 & 0xffff0000u), acc1);
        }
        acc0 = fmaxf(acc0, 0.f);
        acc1 = fmaxf(acc1, 0.f);
        __syncthreads();
        ((float2*)(io + (size_t)(base + nl) * DD))[h] = make_float2(acc0, acc1);
    }
}

extern "C" void kernel_launch(void* const* d_in, const int* in_sizes, int n_in,
                              void* d_out, int out_size, void* d_ws, size_t ws_size,
                              hipStream_t stream) {
    const float* x  = (const float*)d_in[0];
    const int*   ei = (const int*)d_in[1];
    const float* Wl = (const float*)d_in[2];
    const float* bl = (const float*)d_in[3];
    const float* Wr = (const float*)d_in[4];
    float* agg = (float*)d_out;  // d_out doubles as the f32 agg buffer

    // ws layout: deg | row_ptr | cursor | csr | part | wb | xb
    u32* deg     = (u32*)d_ws;
    u32* row_ptr = deg + NNODES;
    u32* cursor  = row_ptr + NNODES;
    u32* csr     = cursor + NNODES;
    u32* part    = csr + NEDGES;
    u32* wb      = part + 256;
    u32* xb      = wb + 16384;
    const size_t need =
        ((size_t)(3 * NNODES + NEDGES + 256 + 16384) + (size_t)NNODES * 64) * 4;

    if (ws_size >= need) {
        hipMemsetAsync(deg, 0, (size_t)NNODES * sizeof(u32), stream);
        prep_wb_k<<<64, 256, 0, stream>>>(Wl, Wr, wb);
        xconv_k<<<12500, 256, 0, stream>>>(x, xb);
        hist_k<<<3125, 256, 0, stream>>>(ei, deg);
        scan1_k<<<SCAN_B, 256, 0, stream>>>(deg, part);
        scan2_k<<<1, 256, 0, stream>>>(part);
        scan3_k<<<SCAN_B, 256, 0, stream>>>(deg, part, row_ptr, cursor);
        fill_k<<<3125, 256, 0, stream>>>(ei, cursor, csr);
        gatherb2_k<<<12500, 256, 0, stream>>>(xb, csr, row_ptr, deg, agg);
        mfma_fused_k<<<(NNODES + 127) / 128, 256, 0, stream>>>(agg, xb, wb, bl, agg);
    } else {
        hipMemsetAsync(d_out, 0, (size_t)NNODES * DD * sizeof(float), stream);
        hipMemsetAsync(d_ws, 0, (size_t)NNODES * sizeof(u32), stream);
        scatter_k<<<(NEDGES * 64) / 256, 256, 0, stream>>>(x, ei, agg, deg);
        mean_k<<<(NNODES * 64 + 255) / 256, 256, 0, stream>>>(agg, deg);
        lin_l_k<<<1024, 256, 0, stream>>>(agg, Wl, bl);
        lin_r_k<<<1024, 256, 0, stream>>>(agg, x, Wr);
    }
}

// Round 6
// 224.115 us; speedup vs baseline: 3.9572x; 1.0265x over previous
//
#include <hip/hip_runtime.h>
#include <hip/hip_bf16.h>

#define NNODES 50000
#define NEDGES 800000
#define DD 128
#define SCAN_B 196   // ceil(50000/256)
#define WPITCH 129   // dwords per W row in LDS (odd -> bank hop 1)
#define NPART 8      // dst partitions (one per XCD)
#define PSIZE 6250   // nodes per partition

typedef unsigned int u32;
typedef unsigned short u16;
typedef short bf16x8 __attribute__((ext_vector_type(8)));
typedef float f32x4 __attribute__((ext_vector_type(4)));

union U4B8 {
    uint4 u;
    bf16x8 b;
};

__device__ __forceinline__ u16 f2b(float f) {
    u32 u = __float_as_uint(f);
    u32 rounding = 0x7fffu + ((u >> 16) & 1u);
    return (u16)((u + rounding) >> 16);
}

// ---------------------------------------------------------------------------
// Prep A: Wb[o][k] bf16 pairs, o=0..127, k=0..255 (k<128 -> Wl, k>=128 -> Wr).
// ---------------------------------------------------------------------------
__global__ __launch_bounds__(256) void prep_wb_k(
    const float* __restrict__ Wl, const float* __restrict__ Wr,
    u32* __restrict__ wb) {
    int idx = blockIdx.x * 256 + threadIdx.x;
    if (idx >= 16384) return;
    int o = idx >> 7, c = idx & 127;
    int k0 = 2 * c;
    const float* src = (k0 < DD) ? (Wl + o * DD + k0) : (Wr + o * DD + (k0 - DD));
    u32 lo = f2b(src[0]);
    u32 hi = f2b(src[1]);
    wb[idx] = lo | (hi << 16);
}

// ---------------------------------------------------------------------------
// Prep B: x -> packed bf16 rows.
// ---------------------------------------------------------------------------
__global__ __launch_bounds__(256) void xconv_k(
    const float* __restrict__ x, u32* __restrict__ xb) {
    int i = blockIdx.x * 256 + threadIdx.x;  // 50000*64 exactly
    float2 v = ((const float2*)x)[i];
    xb[i] = (u32)f2b(v.x) | ((u32)f2b(v.y) << 16);
}

// ---------------------------------------------------------------------------
// CSR build, dst-partitioned: part = blockIdx & 7 so consecutive blocks land
// on different XCDs; each partition's counters/csr range stay XCD-L2-local
// (kills the 16x cross-XCD write amplification seen in the flat version).
// ---------------------------------------------------------------------------
__global__ __launch_bounds__(256) void hist_part_k(
    const int* __restrict__ ei, u32* __restrict__ deg) {
    u32 part = blockIdx.x & (NPART - 1);
    u32 e = (blockIdx.x >> 3) * 256u + threadIdx.x;
    if (e >= NEDGES) return;
    int dst = ei[NEDGES + e];
    if ((u32)(dst - part * PSIZE) < (u32)PSIZE)
        atomicAdd(deg + dst, 1u);
}

__global__ __launch_bounds__(256) void scan1_k(
    const u32* __restrict__ deg, u32* __restrict__ part) {
    __shared__ u32 s[256];
    int i = blockIdx.x * 256 + threadIdx.x;
    int t = threadIdx.x;
    s[t] = (i < NNODES) ? deg[i] : 0u;
    __syncthreads();
    for (int off = 128; off > 0; off >>= 1) {
        if (t < off) s[t] += s[t + off];
        __syncthreads();
    }
    if (t == 0) part[blockIdx.x] = s[0];
}

__global__ __launch_bounds__(256) void scan2_k(u32* __restrict__ part) {
    __shared__ u32 s[256];
    int t = threadIdx.x;
    u32 v = (t < SCAN_B) ? part[t] : 0u;
    s[t] = v;
    __syncthreads();
    for (int off = 1; off < 256; off <<= 1) {
        u32 a = (t >= off) ? s[t - off] : 0u;
        __syncthreads();
        s[t] += a;
        __syncthreads();
    }
    if (t < SCAN_B) part[t] = s[t] - v;  // exclusive
}

__global__ __launch_bounds__(256) void scan3_k(
    const u32* __restrict__ deg, const u32* __restrict__ part,
    u32* __restrict__ row_ptr, u32* __restrict__ cursor) {
    __shared__ u32 s[256];
    int i = blockIdx.x * 256 + threadIdx.x;
    int t = threadIdx.x;
    u32 v = (i < NNODES) ? deg[i] : 0u;
    s[t] = v;
    __syncthreads();
    for (int off = 1; off < 256; off <<= 1) {
        u32 a = (t >= off) ? s[t - off] : 0u;
        __syncthreads();
        s[t] += a;
        __syncthreads();
    }
    if (i < NNODES) {
        u32 e = part[blockIdx.x] + s[t] - v;
        row_ptr[i] = e;
        cursor[i] = e;
    }
}

__global__ __launch_bounds__(256) void fill_part_k(
    const int* __restrict__ ei, u32* __restrict__ cursor,
    u32* __restrict__ csr) {
    u32 part = blockIdx.x & (NPART - 1);
    u32 e = (blockIdx.x >> 3) * 256u + threadIdx.x;
    if (e >= NEDGES) return;
    int dst = ei[NEDGES + e];
    if ((u32)(dst - part * PSIZE) < (u32)PSIZE) {
        u32 pos = atomicAdd(cursor + dst, 1u);
        csr[pos] = (u32)ei[e];
    }
}

// ---------------------------------------------------------------------------
// Gather-mean: coalesced csr block read + shfl broadcast; x8 unroll for MLP.
// ---------------------------------------------------------------------------
__global__ __launch_bounds__(256) void gatherb2_k(
    const u32* __restrict__ xb, const u32* __restrict__ csr,
    const u32* __restrict__ row_ptr, const u32* __restrict__ deg,
    float* __restrict__ agg) {
    u32 gid = blockIdx.x * 256u + threadIdx.x;
    u32 node = gid >> 6;
    u32 lane = gid & 63u;
    if (node >= NNODES) return;
    u32 d = deg[node];
    u32 beg = row_ptr[node], end = beg + d;
    float a0 = 0.f, a1 = 0.f;
    for (u32 i = beg; i < end; i += 64u) {
        u32 cnt = min(64u, end - i);
        u32 idx = i + lane;
        u32 sv = csr[idx < end ? idx : (end - 1)];  // coalesced block read
        u32 j = 0;
        for (; j + 8 <= cnt; j += 8) {
            u32 s0 = __shfl(sv, (int)(j + 0), 64);
            u32 s1 = __shfl(sv, (int)(j + 1), 64);
            u32 s2 = __shfl(sv, (int)(j + 2), 64);
            u32 s3 = __shfl(sv, (int)(j + 3), 64);
            u32 s4 = __shfl(sv, (int)(j + 4), 64);
            u32 s5 = __shfl(sv, (int)(j + 5), 64);
            u32 s6 = __shfl(sv, (int)(j + 6), 64);
            u32 s7 = __shfl(sv, (int)(j + 7), 64);
            u32 v0 = xb[(size_t)s0 * 64 + lane];
            u32 v1 = xb[(size_t)s1 * 64 + lane];
            u32 v2 = xb[(size_t)s2 * 64 + lane];
            u32 v3 = xb[(size_t)s3 * 64 + lane];
            u32 v4 = xb[(size_t)s4 * 64 + lane];
            u32 v5 = xb[(size_t)s5 * 64 + lane];
            u32 v6 = xb[(size_t)s6 * 64 + lane];
            u32 v7 = xb[(size_t)s7 * 64 + lane];
            a0 += __uint_as_float(v0 << 16);
            a1 += __uint_as_float(v0 & 0xffff0000u);
            a0 += __uint_as_float(v1 << 16);
            a1 += __uint_as_float(v1 & 0xffff0000u);
            a0 += __uint_as_float(v2 << 16);
            a1 += __uint_as_float(v2 & 0xffff0000u);
            a0 += __uint_as_float(v3 << 16);
            a1 += __uint_as_float(v3 & 0xffff0000u);
            a0 += __uint_as_float(v4 << 16);
            a1 += __uint_as_float(v4 & 0xffff0000u);
            a0 += __uint_as_float(v5 << 16);
            a1 += __uint_as_float(v5 & 0xffff0000u);
            a0 += __uint_as_float(v6 << 16);
            a1 += __uint_as_float(v6 & 0xffff0000u);
            a0 += __uint_as_float(v7 << 16);
            a1 += __uint_as_float(v7 & 0xffff0000u);
        }
        for (; j < cnt; ++j) {
            u32 s = __shfl(sv, (int)j, 64);
            u32 v = xb[(size_t)s * 64 + lane];
            a0 += __uint_as_float(v << 16);
            a1 += __uint_as_float(v & 0xffff0000u);
        }
    }
    float inv = 1.0f / fmaxf((float)d, 1.0f);
    ((float2*)(agg + (size_t)node * DD))[lane] = make_float2(a0 * inv, a1 * inv);
}

// ---------------------------------------------------------------------------
// MFMA fused dual-GEMM: out = relu([agg|x]_bf16 @ [Wl;Wr]^T + b), in place
// over d_out (each wave reads only the rows it later writes; reads precede
// stores; clamped tail rows write nothing).
// ---------------------------------------------------------------------------
__global__ __launch_bounds__(256) void mfma_fused_k(
    const float* __restrict__ agg, const u32* __restrict__ xb,
    const u32* __restrict__ wb, const float* __restrict__ bl,
    float* __restrict__ out) {
    __shared__ u32 w_lds[DD * WPITCH];
    __shared__ float sbias[DD];
    const int tid = threadIdx.x;
    for (int r = tid >> 5; r < DD; r += 8) {
        int c = (tid & 31) * 4;
        uint4 v = *(const uint4*)&wb[r * DD + c];
        *(uint4*)&w_lds[r * WPITCH + c] = v;
    }
    if (tid < DD) sbias[tid] = bl[tid];
    __syncthreads();

    const int wave = tid >> 6, lane = tid & 63;
    const int m = lane & 15, quad = lane >> 4;
    const int row0 = blockIdx.x * 128 + wave * 32;

    f32x4 acc[2][8];
#pragma unroll
    for (int t = 0; t < 2; ++t)
#pragma unroll
        for (int nt = 0; nt < 8; ++nt) acc[t][nt] = (f32x4){0.f, 0.f, 0.f, 0.f};

    for (int ks = 0; ks < 8; ++ks) {
        U4B8 af[2];
        if (ks < 4) {
#pragma unroll
            for (int t = 0; t < 2; ++t) {
                int r = row0 + t * 16 + m;
                r = r < NNODES ? r : NNODES - 1;
                const float* p = agg + (size_t)r * DD + ks * 32 + quad * 8;
                float4 lo = *(const float4*)p;
                float4 hi = *(const float4*)(p + 4);
                af[t].u.x = (u32)f2b(lo.x) | ((u32)f2b(lo.y) << 16);
                af[t].u.y = (u32)f2b(lo.z) | ((u32)f2b(lo.w) << 16);
                af[t].u.z = (u32)f2b(hi.x) | ((u32)f2b(hi.y) << 16);
                af[t].u.w = (u32)f2b(hi.z) | ((u32)f2b(hi.w) << 16);
            }
        } else {
#pragma unroll
            for (int t = 0; t < 2; ++t) {
                int r = row0 + t * 16 + m;
                r = r < NNODES ? r : NNODES - 1;
                af[t].u = *(const uint4*)&xb[(size_t)r * 64 + (ks - 4) * 16 + quad * 4];
            }
        }
#pragma unroll
        for (int nt = 0; nt < 8; ++nt) {
            U4B8 bf;
            bf.u = *(const uint4*)&w_lds[(nt * 16 + m) * WPITCH + ks * 16 + quad * 4];
            acc[0][nt] = __builtin_amdgcn_mfma_f32_16x16x32_bf16(
                af[0].b, bf.b, acc[0][nt], 0, 0, 0);
            acc[1][nt] = __builtin_amdgcn_mfma_f32_16x16x32_bf16(
                af[1].b, bf.b, acc[1][nt], 0, 0, 0);
        }
    }
#pragma unroll
    for (int t = 0; t < 2; ++t) {
#pragma unroll
        for (int nt = 0; nt < 8; ++nt) {
            int col = nt * 16 + m;
            float b = sbias[col];
#pragma unroll
            for (int r = 0; r < 4; ++r) {
                int row = row0 + t * 16 + quad * 4 + r;
                if (row < NNODES)
                    out[(size_t)row * DD + col] = fmaxf(acc[t][nt][r] + b, 0.f);
            }
        }
    }
}

// ---------------------------------------------------------------------------
// Small-ws fallback (R2 path)
// ---------------------------------------------------------------------------
__global__ __launch_bounds__(256) void scatter_k(
    const float* __restrict__ x, const int* __restrict__ ei,
    float* __restrict__ agg, u32* __restrict__ deg) {
    u32 gid = blockIdx.x * 256u + threadIdx.x;
    u32 edge = gid >> 6;
    u32 lane = gid & 63u;
    if (edge >= NEDGES) return;
    int src = ei[edge];
    int dst = ei[NEDGES + edge];
    float2 v = ((const float2*)(x + (size_t)src * DD))[lane];
    float* p = agg + (size_t)dst * DD + lane * 2u;
    unsafeAtomicAdd(p, v.x);
    unsafeAtomicAdd(p + 1, v.y);
    if (lane == 0) atomicAdd(deg + dst, 1u);
}

__global__ __launch_bounds__(256) void mean_k(
    float* __restrict__ agg, const u32* __restrict__ deg) {
    u32 gid = blockIdx.x * 256u + threadIdx.x;
    u32 node = gid >> 6;
    u32 lane = gid & 63u;
    if (node >= NNODES) return;
    float inv = 1.0f / fmaxf((float)deg[node], 1.0f);
    float2* p = (float2*)(agg + (size_t)node * DD) + lane;
    float2 v = *p;
    *p = make_float2(v.x * inv, v.y * inv);
}

__global__ __launch_bounds__(256) void lin_l_k(
    float* __restrict__ agg,
    const float* __restrict__ Wl, const float* __restrict__ bl) {
    __shared__ u32 WT[DD * 65];
    __shared__ float rows[4 * DD];
    __shared__ float sbias[DD];
    const int tid = threadIdx.x;
    {
        u16* WTs = (u16*)WT;
        for (int i = tid; i < DD * DD; i += 256) {
            int o = i >> 7, k = i & 127;
            WTs[k * 130 + o] = f2b(Wl[i]);
        }
        if (tid < DD) sbias[tid] = bl[tid];
    }
    __syncthreads();
    const int h = tid & 63;
    const int nl = tid >> 6;
    for (int base = blockIdx.x * 4; base < NNODES; base += gridDim.x * 4) {
        ((float2*)rows)[tid] =
            ((const float2*)(agg + (size_t)(base + (tid >> 6)) * DD))[tid & 63];
        __syncthreads();
        float acc0 = sbias[2 * h], acc1 = sbias[2 * h + 1];
#pragma unroll
        for (int k = 0; k < DD; ++k) {
            float a = rows[nl * DD + k];
            u32 w2 = WT[k * 65 + h];
            acc0 = fmaf(a, __uint_as_float(w2 << 16), acc0);
            acc1 = fmaf(a, __uint_as_float(w2 & 0xffff0000u), acc1);
        }
        __syncthreads();
        ((float2*)(agg + (size_t)(base + nl) * DD))[h] = make_float2(acc0, acc1);
    }
}

__global__ __launch_bounds__(256) void lin_r_k(
    float* __restrict__ io, const float* __restrict__ x,
    const float* __restrict__ Wr) {
    __shared__ u32 WT[DD * 65];
    __shared__ float rows[4 * DD];
    const int tid = threadIdx.x;
    {
        u16* WTs = (u16*)WT;
        for (int i = tid; i < DD * DD; i += 256) {
            int o = i >> 7, k = i & 127;
            WTs[k * 130 + o] = f2b(Wr[i]);
        }
    }
    __syncthreads();
    const int h = tid & 63;
    const int nl = tid >> 6;
    for (int base = blockIdx.x * 4; base < NNODES; base += gridDim.x * 4) {
        ((float2*)rows)[tid] =
            ((const float2*)(x + (size_t)(base + (tid >> 6)) * DD))[tid & 63];
        __syncthreads();
        float2 t2 = ((const float2*)(io + (size_t)(base + nl) * DD))[h];
        float acc0 = t2.x, acc1 = t2.y;
#pragma unroll
        for (int k = 0; k < DD; ++k) {
            float a = rows[nl * DD + k];
            u32 w2 = WT[k * 65 + h];
            acc0 = fmaf(a, __uint_as_float(w2 << 16), acc0);
            acc1 = fmaf(a, __uint_as_float(w2 & 0xffff0000u), acc1);
        }
        acc0 = fmaxf(acc0, 0.f);
        acc1 = fmaxf(acc1, 0.f);
        __syncthreads();
        ((float2*)(io + (size_t)(base + nl) * DD))[h] = make_float2(acc0, acc1);
    }
}

extern "C" void kernel_launch(void* const* d_in, const int* in_sizes, int n_in,
                              void* d_out, int out_size, void* d_ws, size_t ws_size,
                              hipStream_t stream) {
    const float* x  = (const float*)d_in[0];
    const int*   ei = (const int*)d_in[1];
    const float* Wl = (const float*)d_in[2];
    const float* bl = (const float*)d_in[3];
    const float* Wr = (const float*)d_in[4];
    float* agg = (float*)d_out;  // d_out doubles as the f32 agg buffer

    // ws layout: deg | row_ptr | cursor | csr | part | wb | xb
    u32* deg     = (u32*)d_ws;
    u32* row_ptr = deg + NNODES;
    u32* cursor  = row_ptr + NNODES;
    u32* csr     = cursor + NNODES;
    u32* part    = csr + NEDGES;
    u32* wb      = part + 256;
    u32* xb      = wb + 16384;
    const size_t need =
        ((size_t)(3 * NNODES + NEDGES + 256 + 16384) + (size_t)NNODES * 64) * 4;

    if (ws_size >= need) {
        hipMemsetAsync(deg, 0, (size_t)NNODES * sizeof(u32), stream);
        prep_wb_k<<<64, 256, 0, stream>>>(Wl, Wr, wb);
        xconv_k<<<12500, 256, 0, stream>>>(x, xb);
        hist_part_k<<<3125 * NPART, 256, 0, stream>>>(ei, deg);
        scan1_k<<<SCAN_B, 256, 0, stream>>>(deg, part);
        scan2_k<<<1, 256, 0, stream>>>(part);
        scan3_k<<<SCAN_B, 256, 0, stream>>>(deg, part, row_ptr, cursor);
        fill_part_k<<<3125 * NPART, 256, 0, stream>>>(ei, cursor, csr);
        gatherb2_k<<<12500, 256, 0, stream>>>(xb, csr, row_ptr, deg, agg);
        mfma_fused_k<<<(NNODES + 127) / 128, 256, 0, stream>>>(agg, xb, wb, bl, agg);
    } else {
        hipMemsetAsync(d_out, 0, (size_t)NNODES * DD * sizeof(float), stream);
        hipMemsetAsync(d_ws, 0, (size_t)NNODES * sizeof(u32), stream);
        scatter_k<<<(NEDGES * 64) / 256, 256, 0, stream>>>(x, ei, agg, deg);
        mean_k<<<(NNODES * 64 + 255) / 256, 256, 0, stream>>>(agg, deg);
        lin_l_k<<<1024, 256, 0, stream>>>(agg, Wl, bl);
        lin_r_k<<<1024, 256, 0, stream>>>(agg, x, Wr);
    }
}

// Round 7
// 217.928 us; speedup vs baseline: 4.0696x; 1.0284x over previous
//
#include <hip/hip_runtime.h>
#include <hip/hip_bf16.h>

#define NNODES 50000
#define NEDGES 800000
#define DD 128
#define SCAN_B 196   // ceil(50000/256)
#define WPITCH 129   // dwords per W row in LDS (odd -> bank hop 1)
#define NPART 8      // dst partitions (one per XCD)
#define PSIZE 6250   // nodes per partition

typedef unsigned int u32;
typedef unsigned short u16;
typedef short bf16x8 __attribute__((ext_vector_type(8)));
typedef float f32x4 __attribute__((ext_vector_type(4)));

union U4B8 {
    uint4 u;
    bf16x8 b;
};

__device__ __forceinline__ u32 f2b(float f) {
    u32 u = __float_as_uint(f);
    u32 rounding = 0x7fffu + ((u >> 16) & 1u);
    return (u + rounding) >> 16;
}

// ---------------------------------------------------------------------------
// setup_k: one launch doing (a) W pack -> wb[o][kpair] bf16x2, (b) deg zero,
// (c) x -> packed bf16 rows xb. blockIdx-range dispatch.
// ---------------------------------------------------------------------------
__global__ __launch_bounds__(256) void setup_k(
    const float* __restrict__ x, const float* __restrict__ Wl,
    const float* __restrict__ Wr, u32* __restrict__ wb,
    u32* __restrict__ xb, u32* __restrict__ deg) {
    int b = blockIdx.x, tid = threadIdx.x;
    if (b < 64) {
        int idx = b * 256 + tid;  // < 16384
        int o = idx >> 7, c = idx & 127, k0 = 2 * c;
        const float* src = (k0 < DD) ? (Wl + o * DD + k0) : (Wr + o * DD + (k0 - DD));
        wb[idx] = f2b(src[0]) | (f2b(src[1]) << 16);
    } else if (b < 260) {
        int i = (b - 64) * 256 + tid;
        if (i < NNODES) deg[i] = 0u;
    } else {
        int i = (b - 260) * 256 + tid;  // < 3,200,000 exactly
        float2 v = ((const float2*)x)[i];
        xb[i] = f2b(v.x) | (f2b(v.y) << 16);
    }
}

// ---------------------------------------------------------------------------
// CSR build, dst-partitioned (blockIdx&7 -> XCD-local counter/csr ranges).
// ---------------------------------------------------------------------------
__global__ __launch_bounds__(256) void hist_part_k(
    const int* __restrict__ ei, u32* __restrict__ deg) {
    u32 part = blockIdx.x & (NPART - 1);
    u32 e = (blockIdx.x >> 3) * 256u + threadIdx.x;
    if (e >= NEDGES) return;
    int dst = ei[NEDGES + e];
    if ((u32)(dst - part * PSIZE) < (u32)PSIZE)
        atomicAdd(deg + dst, 1u);
}

__global__ __launch_bounds__(256) void scan1_k(
    const u32* __restrict__ deg, u32* __restrict__ part) {
    __shared__ u32 s[256];
    int i = blockIdx.x * 256 + threadIdx.x;
    int t = threadIdx.x;
    s[t] = (i < NNODES) ? deg[i] : 0u;
    __syncthreads();
    for (int off = 128; off > 0; off >>= 1) {
        if (t < off) s[t] += s[t + off];
        __syncthreads();
    }
    if (t == 0) part[blockIdx.x] = s[0];
}

__global__ __launch_bounds__(256) void scan2_k(u32* __restrict__ part) {
    __shared__ u32 s[256];
    int t = threadIdx.x;
    u32 v = (t < SCAN_B) ? part[t] : 0u;
    s[t] = v;
    __syncthreads();
    for (int off = 1; off < 256; off <<= 1) {
        u32 a = (t >= off) ? s[t - off] : 0u;
        __syncthreads();
        s[t] += a;
        __syncthreads();
    }
    if (t < SCAN_B) part[t] = s[t] - v;  // exclusive
}

__global__ __launch_bounds__(256) void scan3_k(
    const u32* __restrict__ deg, const u32* __restrict__ part,
    u32* __restrict__ row_ptr, u32* __restrict__ cursor) {
    __shared__ u32 s[256];
    int i = blockIdx.x * 256 + threadIdx.x;
    int t = threadIdx.x;
    u32 v = (i < NNODES) ? deg[i] : 0u;
    s[t] = v;
    __syncthreads();
    for (int off = 1; off < 256; off <<= 1) {
        u32 a = (t >= off) ? s[t - off] : 0u;
        __syncthreads();
        s[t] += a;
        __syncthreads();
    }
    if (i < NNODES) {
        u32 e = part[blockIdx.x] + s[t] - v;
        row_ptr[i] = e;
        cursor[i] = e;
    }
}

__global__ __launch_bounds__(256) void fill_part_k(
    const int* __restrict__ ei, u32* __restrict__ cursor,
    u32* __restrict__ csr) {
    u32 part = blockIdx.x & (NPART - 1);
    u32 e = (blockIdx.x >> 3) * 256u + threadIdx.x;
    if (e >= NEDGES) return;
    int dst = ei[NEDGES + e];
    if ((u32)(dst - part * PSIZE) < (u32)PSIZE) {
        u32 pos = atomicAdd(cursor + dst, 1u);
        csr[pos] = (u32)ei[e];
    }
}

// ---------------------------------------------------------------------------
// Gather-mean -> packed bf16 aggb rows (feeds MFMA directly).
// Coalesced csr block read + shfl broadcast; x8 unroll for MLP.
// ---------------------------------------------------------------------------
__global__ __launch_bounds__(256) void gatherb3_k(
    const u32* __restrict__ xb, const u32* __restrict__ csr,
    const u32* __restrict__ row_ptr, const u32* __restrict__ deg,
    u32* __restrict__ aggb) {
    u32 gid = blockIdx.x * 256u + threadIdx.x;
    u32 node = gid >> 6;
    u32 lane = gid & 63u;
    if (node >= NNODES) return;
    u32 d = deg[node];
    u32 beg = row_ptr[node], end = beg + d;
    float a0 = 0.f, a1 = 0.f;
    for (u32 i = beg; i < end; i += 64u) {
        u32 cnt = min(64u, end - i);
        u32 idx = i + lane;
        u32 sv = csr[idx < end ? idx : (end - 1)];  // coalesced block read
        u32 j = 0;
        for (; j + 8 <= cnt; j += 8) {
            u32 s0 = __shfl(sv, (int)(j + 0), 64);
            u32 s1 = __shfl(sv, (int)(j + 1), 64);
            u32 s2 = __shfl(sv, (int)(j + 2), 64);
            u32 s3 = __shfl(sv, (int)(j + 3), 64);
            u32 s4 = __shfl(sv, (int)(j + 4), 64);
            u32 s5 = __shfl(sv, (int)(j + 5), 64);
            u32 s6 = __shfl(sv, (int)(j + 6), 64);
            u32 s7 = __shfl(sv, (int)(j + 7), 64);
            u32 v0 = xb[(size_t)s0 * 64 + lane];
            u32 v1 = xb[(size_t)s1 * 64 + lane];
            u32 v2 = xb[(size_t)s2 * 64 + lane];
            u32 v3 = xb[(size_t)s3 * 64 + lane];
            u32 v4 = xb[(size_t)s4 * 64 + lane];
            u32 v5 = xb[(size_t)s5 * 64 + lane];
            u32 v6 = xb[(size_t)s6 * 64 + lane];
            u32 v7 = xb[(size_t)s7 * 64 + lane];
            a0 += __uint_as_float(v0 << 16);
            a1 += __uint_as_float(v0 & 0xffff0000u);
            a0 += __uint_as_float(v1 << 16);
            a1 += __uint_as_float(v1 & 0xffff0000u);
            a0 += __uint_as_float(v2 << 16);
            a1 += __uint_as_float(v2 & 0xffff0000u);
            a0 += __uint_as_float(v3 << 16);
            a1 += __uint_as_float(v3 & 0xffff0000u);
            a0 += __uint_as_float(v4 << 16);
            a1 += __uint_as_float(v4 & 0xffff0000u);
            a0 += __uint_as_float(v5 << 16);
            a1 += __uint_as_float(v5 & 0xffff0000u);
            a0 += __uint_as_float(v6 << 16);
            a1 += __uint_as_float(v6 & 0xffff0000u);
            a0 += __uint_as_float(v7 << 16);
            a1 += __uint_as_float(v7 & 0xffff0000u);
        }
        for (; j < cnt; ++j) {
            u32 s = __shfl(sv, (int)j, 64);
            u32 v = xb[(size_t)s * 64 + lane];
            a0 += __uint_as_float(v << 16);
            a1 += __uint_as_float(v & 0xffff0000u);
        }
    }
    float inv = 1.0f / fmaxf((float)d, 1.0f);
    aggb[(size_t)node * 64 + lane] = f2b(a0 * inv) | (f2b(a1 * inv) << 16);
}

// ---------------------------------------------------------------------------
// MFMA fused dual-GEMM: out = relu([aggb|xb] @ [Wl;Wr]^T + b). Pure bf16
// A-loads from ws; d_out written exactly once (no in-place coupling).
// ---------------------------------------------------------------------------
__global__ __launch_bounds__(256) void mfma_fused_k(
    const u32* __restrict__ aggb, const u32* __restrict__ xb,
    const u32* __restrict__ wb, const float* __restrict__ bl,
    float* __restrict__ out) {
    __shared__ u32 w_lds[DD * WPITCH];
    __shared__ float sbias[DD];
    const int tid = threadIdx.x;
    for (int r = tid >> 5; r < DD; r += 8) {
        int c = (tid & 31) * 4;
        uint4 v = *(const uint4*)&wb[r * DD + c];
        *(uint4*)&w_lds[r * WPITCH + c] = v;
    }
    if (tid < DD) sbias[tid] = bl[tid];
    __syncthreads();

    const int wave = tid >> 6, lane = tid & 63;
    const int m = lane & 15, quad = lane >> 4;
    const int row0 = blockIdx.x * 128 + wave * 32;

    f32x4 acc[2][8];
#pragma unroll
    for (int t = 0; t < 2; ++t)
#pragma unroll
        for (int nt = 0; nt < 8; ++nt) acc[t][nt] = (f32x4){0.f, 0.f, 0.f, 0.f};

    for (int ks = 0; ks < 8; ++ks) {
        const u32* A = (ks < 4) ? aggb : xb;
        const int kc = (ks & 3) * 16 + quad * 4;
        U4B8 af[2];
#pragma unroll
        for (int t = 0; t < 2; ++t) {
            int r = row0 + t * 16 + m;
            r = r < NNODES ? r : NNODES - 1;
            af[t].u = *(const uint4*)&A[(size_t)r * 64 + kc];
        }
#pragma unroll
        for (int nt = 0; nt < 8; ++nt) {
            U4B8 bf;
            bf.u = *(const uint4*)&w_lds[(nt * 16 + m) * WPITCH + ks * 16 + quad * 4];
            acc[0][nt] = __builtin_amdgcn_mfma_f32_16x16x32_bf16(
                af[0].b, bf.b, acc[0][nt], 0, 0, 0);
            acc[1][nt] = __builtin_amdgcn_mfma_f32_16x16x32_bf16(
                af[1].b, bf.b, acc[1][nt], 0, 0, 0);
        }
    }
#pragma unroll
    for (int t = 0; t < 2; ++t) {
#pragma unroll
        for (int nt = 0; nt < 8; ++nt) {
            int col = nt * 16 + m;
            float b = sbias[col];
#pragma unroll
            for (int r = 0; r < 4; ++r) {
                int row = row0 + t * 16 + quad * 4 + r;
                if (row < NNODES)
                    out[(size_t)row * DD + col] = fmaxf(acc[t][nt][r] + b, 0.f);
            }
        }
    }
}

// ---------------------------------------------------------------------------
// Small-ws fallback (R2 path)
// ---------------------------------------------------------------------------
__global__ __launch_bounds__(256) void scatter_k(
    const float* __restrict__ x, const int* __restrict__ ei,
    float* __restrict__ agg, u32* __restrict__ deg) {
    u32 gid = blockIdx.x * 256u + threadIdx.x;
    u32 edge = gid >> 6;
    u32 lane = gid & 63u;
    if (edge >= NEDGES) return;
    int src = ei[edge];
    int dst = ei[NEDGES + edge];
    float2 v = ((const float2*)(x + (size_t)src * DD))[lane];
    float* p = agg + (size_t)dst * DD + lane * 2u;
    unsafeAtomicAdd(p, v.x);
    unsafeAtomicAdd(p + 1, v.y);
    if (lane == 0) atomicAdd(deg + dst, 1u);
}

__global__ __launch_bounds__(256) void mean_k(
    float* __restrict__ agg, const u32* __restrict__ deg) {
    u32 gid = blockIdx.x * 256u + threadIdx.x;
    u32 node = gid >> 6;
    u32 lane = gid & 63u;
    if (node >= NNODES) return;
    float inv = 1.0f / fmaxf((float)deg[node], 1.0f);
    float2* p = (float2*)(agg + (size_t)node * DD) + lane;
    float2 v = *p;
    *p = make_float2(v.x * inv, v.y * inv);
}

__global__ __launch_bounds__(256) void lin_l_k(
    float* __restrict__ agg,
    const float* __restrict__ Wl, const float* __restrict__ bl) {
    __shared__ u32 WT[DD * 65];
    __shared__ float rows[4 * DD];
    __shared__ float sbias[DD];
    const int tid = threadIdx.x;
    {
        u16* WTs = (u16*)WT;
        for (int i = tid; i < DD * DD; i += 256) {
            int o = i >> 7, k = i & 127;
            WTs[k * 130 + o] = (u16)f2b(Wl[i]);
        }
        if (tid < DD) sbias[tid] = bl[tid];
    }
    __syncthreads();
    const int h = tid & 63;
    const int nl = tid >> 6;
    for (int base = blockIdx.x * 4; base < NNODES; base += gridDim.x * 4) {
        ((float2*)rows)[tid] =
            ((const float2*)(agg + (size_t)(base + (tid >> 6)) * DD))[tid & 63];
        __syncthreads();
        float acc0 = sbias[2 * h], acc1 = sbias[2 * h + 1];
#pragma unroll
        for (int k = 0; k < DD; ++k) {
            float a = rows[nl * DD + k];
            u32 w2 = WT[k * 65 + h];
            acc0 = fmaf(a, __uint_as_float(w2 << 16), acc0);
            acc1 = fmaf(a, __uint_as_float(w2 & 0xffff0000u), acc1);
        }
        __syncthreads();
        ((float2*)(agg + (size_t)(base + nl) * DD))[h] = make_float2(acc0, acc1);
    }
}

__global__ __launch_bounds__(256) void lin_r_k(
    float* __restrict__ io, const float* __restrict__ x,
    const float* __restrict__ Wr) {
    __shared__ u32 WT[DD * 65];
    __shared__ float rows[4 * DD];
    const int tid = threadIdx.x;
    {
        u16* WTs = (u16*)WT;
        for (int i = tid; i < DD * DD; i += 256) {
            int o = i >> 7, k = i & 127;
            WTs[k * 130 + o] = (u16)f2b(Wr[i]);
        }
    }
    __syncthreads();
    const int h = tid & 63;
    const int nl = tid >> 6;
    for (int base = blockIdx.x * 4; base < NNODES; base += gridDim.x * 4) {
        ((float2*)rows)[tid] =
            ((const float2*)(x + (size_t)(base + (tid >> 6)) * DD))[tid & 63];
        __syncthreads();
        float2 t2 = ((const float2*)(io + (size_t)(base + nl) * DD))[h];
        float acc0 = t2.x, acc1 = t2.y;
#pragma unroll
        for (int k = 0; k < DD; ++k) {
            float a = rows[nl * DD + k];
            u32 w2 = WT[k * 65 + h];
            acc0 = fmaf(a, __uint_as_float(w2 << 16), acc0);
            acc1 = fmaf(a, __uint_as_float(w2 & 0xffff0000u), acc1);
        }
        acc0 = fmaxf(acc0, 0.f);
        acc1 = fmaxf(acc1, 0.f);
        __syncthreads();
        ((float2*)(io + (size_t)(base + nl) * DD))[h] = make_float2(acc0, acc1);
    }
}

extern "C" void kernel_launch(void* const* d_in, const int* in_sizes, int n_in,
                              void* d_out, int out_size, void* d_ws, size_t ws_size,
                              hipStream_t stream) {
    const float* x  = (const float*)d_in[0];
    const int*   ei = (const int*)d_in[1];
    const float* Wl = (const float*)d_in[2];
    const float* bl = (const float*)d_in[3];
    const float* Wr = (const float*)d_in[4];

    // ws layout: deg | row_ptr | cursor | csr | part | wb | xb | aggb
    u32* deg     = (u32*)d_ws;
    u32* row_ptr = deg + NNODES;
    u32* cursor  = row_ptr + NNODES;
    u32* csr     = cursor + NNODES;
    u32* part    = csr + NEDGES;
    u32* wb      = part + 256;
    u32* xb      = wb + 16384;
    u32* aggb    = xb + (size_t)NNODES * 64;
    const size_t need =
        ((size_t)(3 * NNODES + NEDGES + 256 + 16384) + (size_t)NNODES * 128) * 4;

    if (ws_size >= need) {
        setup_k<<<12760, 256, 0, stream>>>(x, Wl, Wr, wb, xb, deg);
        hist_part_k<<<3125 * NPART, 256, 0, stream>>>(ei, deg);
        scan1_k<<<SCAN_B, 256, 0, stream>>>(deg, part);
        scan2_k<<<1, 256, 0, stream>>>(part);
        scan3_k<<<SCAN_B, 256, 0, stream>>>(deg, part, row_ptr, cursor);
        fill_part_k<<<3125 * NPART, 256, 0, stream>>>(ei, cursor, csr);
        gatherb3_k<<<12500, 256, 0, stream>>>(xb, csr, row_ptr, deg, aggb);
        mfma_fused_k<<<(NNODES + 127) / 128, 256, 0, stream>>>(
            aggb, xb, wb, bl, (float*)d_out);
    } else {
        float* agg = (float*)d_out;
        hipMemsetAsync(d_out, 0, (size_t)NNODES * DD * sizeof(float), stream);
        hipMemsetAsync(d_ws, 0, (size_t)NNODES * sizeof(u32), stream);
        scatter_k<<<(NEDGES * 64) / 256, 256, 0, stream>>>(x, ei, agg, deg);
        mean_k<<<(NNODES * 64 + 255) / 256, 256, 0, stream>>>(agg, deg);
        lin_l_k<<<1024, 256, 0, stream>>>(agg, Wl, bl);
        lin_r_k<<<1024, 256, 0, stream>>>(agg, x, Wr);
    }
}